// Round 4
// baseline (236.554 us; speedup 1.0000x reference)
//
#include <hip/hip_runtime.h>
#include <hip/hip_bf16.h>
#include <hip/hip_fp16.h>

#define N_NODES 50000
#define N_EDGES 400000
#define D 16
#define HID 64

#define SCAN_B 256
#define SCAN_G ((N_NODES + SCAN_B - 1) / SCAN_B)   // 196

typedef unsigned short ushort_t;

// ---------------- int-indexed workspace layout (CSR path) ----------------
#define CNT4_OFF  0                       // [4][N] replicated counts (memset to 0)
#define DEG_OFF   (4 * N_NODES)           // [N] total degree
#define OFF_OFF   (5 * N_NODES)           // [N+1] CSR offsets
#define CUR_OFF   (6 * N_NODES + 1)       // [N] claim cursors
#define BS_OFF    (7 * N_NODES + 1)       // [SCAN_G] block sums
#define MSG_OFF_I (((BS_OFF + SCAN_G) + 3) & ~3)  // [2E*16] fp32 msgs
// f32 weight table: 64 j-rows x 64 dwords (256B, 16B-aligned rows)
//   [0..31]  W1[j][k] f32    [32..47] W2[i][j] f32 (i=0..15)
//   [48]     b1[j]           [49..63] pad
// then 16 dwords of b2 (f32)
#define PREP_OFF  (MSG_OFF_I + 2 * N_EDGES * D)
#define PREP_DW   (64 * 64 + 16)
#define CSR_NEEDED_BYTES ((size_t)(PREP_OFF + PREP_DW) * 4 + 64)

// ---------------- fallback (atomic) layout ----------------
#define FB_NDEG   (N_NODES)
#define FB_NACC   (N_NODES * D)
#define FB_FLAGS  (FB_NDEG + FB_NACC)

// ---------------------------------------------------------------------------
// dtype helpers
// ---------------------------------------------------------------------------
__device__ __forceinline__ float bf_bits(ushort_t us) {
    return __uint_as_float(((unsigned)us) << 16);
}
__device__ __forceinline__ float lo_bf(unsigned u) { return __uint_as_float(u << 16); }
__device__ __forceinline__ float hi_bf(unsigned u) { return __uint_as_float(u & 0xffff0000u); }
__device__ __forceinline__ ushort_t f2bf(float v) {
    unsigned u = __float_as_uint(v);
    unsigned r = (u + 0x7fffu + ((u >> 16) & 1u)) >> 16;
    return (ushort_t)r;
}
__device__ __forceinline__ float ld_f(const void* p, int idx, int f32) {
    return f32 ? ((const float*)p)[idx]
               : bf_bits(((const ushort_t*)p)[idx]);
}

__device__ __forceinline__ void load16(const void* __restrict__ p, long long base,
                                       int f32, float* o) {
    if (f32) {
        const float4* q = (const float4*)((const float*)p + base);
        float4 a = q[0], b = q[1], c = q[2], d = q[3];
        o[0]=a.x; o[1]=a.y; o[2]=a.z; o[3]=a.w;
        o[4]=b.x; o[5]=b.y; o[6]=b.z; o[7]=b.w;
        o[8]=c.x; o[9]=c.y; o[10]=c.z; o[11]=c.w;
        o[12]=d.x; o[13]=d.y; o[14]=d.z; o[15]=d.w;
    } else {
        const uint4* q = (const uint4*)((const ushort_t*)p + base);
        uint4 a = q[0], b = q[1];
        unsigned u[8] = {a.x, a.y, a.z, a.w, b.x, b.y, b.z, b.w};
#pragma unroll
        for (int k = 0; k < 8; k++) {
            o[2 * k]     = lo_bf(u[k]);
            o[2 * k + 1] = hi_bf(u[k]);
        }
    }
}

__device__ __forceinline__ void load_edge(const void* __restrict__ ei, int e, int is64,
                                          int& s, int& d) {
    if (is64) {
        const long long* p = (const long long*)ei;
        s = (int)p[e];
        d = (int)p[N_EDGES + e];
    } else {
        const int* p = (const int*)ei;
        s = p[e];
        d = p[N_EDGES + e];
    }
}

// Parallel flag detection: first wave (64 lanes) checks 256 x-values (4 each)
// and the first 16 edge int64s via ballot.
__device__ __forceinline__ void detect_flags_par(const void* x, const void* ei,
                                                 int* flags) {
    int t = threadIdx.x;
    if (t < 64) {
        const ushort_t* h = (const ushort_t*)x;
        int bad = 0;
#pragma unroll
        for (int k = 0; k < 4; k++) {
            float v = bf_bits(h[4 * t + k]);
            if (!(v == v) || fabsf(v) > 1.0e6f) bad = 1;
        }
        unsigned long long mb = __ballot(bad);
        const long long* p = (const long long*)ei;
        int bad64 = 0;
        if (t < 16) {
            long long v = p[t];
            bad64 = (v < 0 || v >= N_NODES) ? 1 : 0;
        }
        unsigned long long m64 = __ballot(bad64);
        if (t == 0) {
            flags[0] = mb ? 1 : 0;
            flags[1] = m64 ? 0 : 1;
        }
    }
}

__device__ __forceinline__ void stage_weights(
    const void* W1, const void* b1, const void* W2, const void* b2, int f32,
    float* sW1, float* sW2t, float* sb1, float* sb2)
{
    int t = threadIdx.x;
    for (int idx = t; idx < HID * 2 * D; idx += blockDim.x)
        sW1[idx] = ld_f(W1, idx, f32);
    for (int idx = t; idx < HID * D; idx += blockDim.x) {
        int j = idx / D, i = idx % D;
        sW2t[idx] = ld_f(W2, i * HID + j, f32);
    }
    if (t < HID) sb1[t] = ld_f(b1, t, f32);
    if (t < D)  sb2[t] = ld_f(b2, t, f32);
}

// ---------------------------------------------------------------------------
// Full-MLP per-edge math, f32 (safety + fallback paths)
// ---------------------------------------------------------------------------
__device__ __forceinline__ void edge_math_v4(
    const float* __restrict__ sW1, const float* __restrict__ sW2t,
    const float* __restrict__ sb1, const float* __restrict__ sb2,
    const float* xs, const float* xd, float coef,
    float* ms, float* md)
{
    float vs[D], vd[D];
#pragma unroll
    for (int i = 0; i < D; i++) { vs[i] = sb2[i]; vd[i] = sb2[i]; }
#pragma unroll 4
    for (int j = 0; j < HID; j++) {
        float hs = sb1[j], hd = sb1[j];
        const float4* w4 = (const float4*)&sW1[j * 2 * D];
#pragma unroll
        for (int t = 0; t < 4; t++) {
            float4 wv = w4[t];
            int k = 4 * t;
            hs = fmaf(wv.x, xs[k],     hs); hd = fmaf(wv.x, xd[k],     hd);
            hs = fmaf(wv.y, xs[k + 1], hs); hd = fmaf(wv.y, xd[k + 1], hd);
            hs = fmaf(wv.z, xs[k + 2], hs); hd = fmaf(wv.z, xd[k + 2], hd);
            hs = fmaf(wv.w, xs[k + 3], hs); hd = fmaf(wv.w, xd[k + 3], hd);
        }
#pragma unroll
        for (int t = 0; t < 4; t++) {
            float4 wv = w4[4 + t];
            int k = 4 * t;
            hs = fmaf(wv.x, xd[k],     hs); hd = fmaf(wv.x, xs[k],     hd);
            hs = fmaf(wv.y, xd[k + 1], hs); hd = fmaf(wv.y, xs[k + 1], hd);
            hs = fmaf(wv.z, xd[k + 2], hs); hd = fmaf(wv.z, xs[k + 2], hd);
            hs = fmaf(wv.w, xd[k + 3], hs); hd = fmaf(wv.w, xs[k + 3], hd);
        }
        hs = fmaxf(hs, 0.0f);
        hd = fmaxf(hd, 0.0f);
        const float4* w24 = (const float4*)&sW2t[j * D];
#pragma unroll
        for (int t = 0; t < 4; t++) {
            float4 u = w24[t];
            int i = 4 * t;
            vs[i]     = fmaf(u.x, hs, vs[i]);     vd[i]     = fmaf(u.x, hd, vd[i]);
            vs[i + 1] = fmaf(u.y, hs, vs[i + 1]); vd[i + 1] = fmaf(u.y, hd, vd[i + 1]);
            vs[i + 2] = fmaf(u.z, hs, vs[i + 2]); vd[i + 2] = fmaf(u.z, hd, vd[i + 2]);
            vs[i + 3] = fmaf(u.w, hs, vs[i + 3]); vd[i + 3] = fmaf(u.w, hd, vd[i + 3]);
        }
    }
    float ns = 0.0f, nd = 0.0f;
#pragma unroll
    for (int i = 0; i < D; i++) { ns = fmaf(vs[i], vs[i], ns); nd = fmaf(vd[i], vd[i], nd); }
    float is_ = 1.0f / fmaxf(sqrtf(ns), 1e-12f);
    float id_ = 1.0f / fmaxf(sqrtf(nd), 1e-12f);
#pragma unroll
    for (int i = 0; i < D; i++) { vs[i] *= is_; vd[i] *= id_; }
    float dot1 = 0.0f;
#pragma unroll
    for (int i = 0; i < D; i++) dot1 = fmaf(vd[i], xd[i], dot1);
#pragma unroll
    for (int i = 0; i < D; i++) ms[i] = fmaf(-2.0f * dot1, vd[i], xd[i]);
    float dot2 = 0.0f;
#pragma unroll
    for (int i = 0; i < D; i++) dot2 = fmaf(vs[i], ms[i], dot2);
#pragma unroll
    for (int i = 0; i < D; i++) ms[i] = coef * fmaf(-2.0f * dot2, vs[i], ms[i]);
    float dot3 = 0.0f;
#pragma unroll
    for (int i = 0; i < D; i++) dot3 = fmaf(vs[i], xs[i], dot3);
#pragma unroll
    for (int i = 0; i < D; i++) md[i] = fmaf(-2.0f * dot3, vs[i], xs[i]);
    float dot4 = 0.0f;
#pragma unroll
    for (int i = 0; i < D; i++) dot4 = fmaf(vd[i], md[i], dot4);
#pragma unroll
    for (int i = 0; i < D; i++) md[i] = coef * fmaf(-2.0f * dot4, vd[i], md[i]);
}

// ===========================================================================
// CSR path kernels
// ===========================================================================
// Counting + (block 0 only) packing the f32 weight table into ws.
__global__ void csr_count_kernel(const void* __restrict__ ei,
                                 const void* __restrict__ x,
                                 const void* __restrict__ W1,
                                 const void* __restrict__ b1,
                                 const void* __restrict__ W2,
                                 const void* __restrict__ b2,
                                 int* __restrict__ wsI) {
    __shared__ int sfl[2];
    detect_flags_par(x, ei, sfl);
    __syncthreads();
    int i64 = sfl[1];

    if (blockIdx.x == 0) {
        // pack f32 weight table (bf16 interpretation; unused by the f32 path)
        float* pf = (float*)(wsI + PREP_OFF);
        const ushort_t* W1b = (const ushort_t*)W1;
        const ushort_t* W2b = (const ushort_t*)W2;
        const ushort_t* b1b = (const ushort_t*)b1;
        const ushort_t* b2b = (const ushort_t*)b2;
        for (int idx = threadIdx.x; idx < 64 * 64; idx += 256) {
            int j = idx >> 6, w = idx & 63;
            float val = 0.0f;
            if (w < 32)      val = bf_bits(W1b[j * 32 + w]);
            else if (w < 48) val = bf_bits(W2b[(w - 32) * HID + j]);
            else if (w == 48) val = bf_bits(b1b[j]);
            pf[idx] = val;
        }
        if (threadIdx.x < D)
            pf[64 * 64 + threadIdx.x] = bf_bits(b2b[threadIdx.x]);
    }

    int e = blockIdx.x * blockDim.x + threadIdx.x;
    if (e >= N_EDGES) return;
    int s, d;
    load_edge(ei, e, i64, s, d);
    int r = (e & 3) * N_NODES;
    atomicAdd(&wsI[CNT4_OFF + r + s], 1);
    atomicAdd(&wsI[CNT4_OFF + r + d], 1);
}

__global__ __launch_bounds__(SCAN_B) void csr_scan1_kernel(int* __restrict__ wsI) {
    __shared__ int sm[SCAN_B];
    int t = threadIdx.x;
    int g = blockIdx.x * SCAN_B + t;
    int c = 0;
    if (g < N_NODES) {
        c = wsI[CNT4_OFF + g] + wsI[CNT4_OFF + N_NODES + g]
          + wsI[CNT4_OFF + 2 * N_NODES + g] + wsI[CNT4_OFF + 3 * N_NODES + g];
        wsI[DEG_OFF + g] = c;
    }
    sm[t] = c;
    __syncthreads();
    for (int st = SCAN_B / 2; st > 0; st >>= 1) {
        if (t < st) sm[t] += sm[t + st];
        __syncthreads();
    }
    if (t == 0) wsI[BS_OFF + blockIdx.x] = sm[0];
}

__global__ __launch_bounds__(SCAN_B) void csr_scan3_kernel(int* __restrict__ wsI) {
    __shared__ int sB[SCAN_B];
    __shared__ int sm[SCAN_B];
    int t = threadIdx.x;
    int bsv = (t < SCAN_G) ? wsI[BS_OFF + t] : 0;
    sB[t] = bsv;
    __syncthreads();
    for (int st = 1; st < SCAN_B; st <<= 1) {
        int u = (t >= st) ? sB[t - st] : 0;
        __syncthreads();
        sB[t] += u;
        __syncthreads();
    }
    int blockBase = sB[blockIdx.x] - wsI[BS_OFF + blockIdx.x];

    int g = blockIdx.x * SCAN_B + t;
    int c = (g < N_NODES) ? wsI[DEG_OFF + g] : 0;
    sm[t] = c;
    __syncthreads();
    for (int st = 1; st < SCAN_B; st <<= 1) {
        int u = (t >= st) ? sm[t - st] : 0;
        __syncthreads();
        sm[t] += u;
        __syncthreads();
    }
    int excl = sm[t] - c + blockBase;
    if (g < N_NODES) {
        wsI[OFF_OFF + g] = excl;
        wsI[CUR_OFF + g] = excl;
        if (g == N_NODES - 1) wsI[OFF_OFF + N_NODES] = excl + c;
    }
}

// ---------------------------------------------------------------------------
// Edge kernel, 2 LANES PER EDGE.
// R0/R2/R3 post-mortem: three different math formulations all pinned at
// ~92-98 us with OccupancyPercent ~29% (grid = 6250 waves -> ~2-6 waves/SIMD
// time-avg) -> latency-bound from TLP shortage, not VALU-throughput-bound.
// Fix: lane pair (even,odd) splits the two reflection orientations. Each
// lane: h = W1.[xa|xb] (unified, branch-free), own v + normalize, shfl_xor
// partner's v, one Householder epilogue -> one message. Wave count 2x
// (12500 -> ~12 waves/SIMD), per-lane FMA halves, atomic slot-claim issued
// BEFORE the math (latency hides under ~6k cycles of FMA), 1 atomic + 4
// stores per lane. Every float chain keeps the exact R3 op order -> absmax
// unchanged.
// ---------------------------------------------------------------------------
__global__ __launch_bounds__(256) void csr_edge_kernel(
    const void* __restrict__ x,
    const void* __restrict__ ei,
    const void* __restrict__ W1,
    const void* __restrict__ b1,
    const void* __restrict__ W2,
    const void* __restrict__ b2,
    const float* __restrict__ prep,
    int* __restrict__ wsI)
{
    __shared__ __align__(16) float sW1f[HID * 2 * D];   // f32 path only
    __shared__ __align__(16) float sW2tf[HID * D];      // f32 path only
    __shared__ float sb1[HID];
    __shared__ float sb2[D];
    __shared__ int sfl[2];

    detect_flags_par(x, ei, sfl);
    __syncthreads();
    int f32 = sfl[0], i64 = sfl[1];
    int t = threadIdx.x;

    int gid = blockIdx.x * 256 + t;       // 0 .. 2E-1 (exact, 3125 blocks)
    int e = gid >> 1;
    int which = gid & 1;                  // 0: s-side message, 1: d-side
    float* msg = (float*)(wsI + MSG_OFF_I);

    if (f32) {
        // ---------------- f32 safety path (unchanged math, lane-even only) ----
        for (int idx = t; idx < HID * 2 * D; idx += 256)
            sW1f[idx] = ld_f(W1, idx, 1);
        for (int idx = t; idx < HID * D; idx += 256) {
            int j = idx / D, i = idx % D;
            sW2tf[idx] = ld_f(W2, i * HID + j, 1);
        }
        if (t < HID) sb1[t] = ld_f(b1, t, 1);
        if (t < D)  sb2[t] = ld_f(b2, t, 1);
        __syncthreads();

        if (which || e >= N_EDGES) return;
        int s, d;
        load_edge(ei, e, i64, s, d);
        float degs = (float)wsI[DEG_OFF + s];
        float degd = (float)wsI[DEG_OFF + d];
        float coef = (1.0f / sqrtf(fmaxf(degs, 1e-5f))) * (1.0f / sqrtf(fmaxf(degd, 1e-5f)));
        float xs[D], xd[D];
        load16(x, (long long)s * D, 1, xs);
        load16(x, (long long)d * D, 1, xd);
        float ms[D], md[D];
        edge_math_v4(sW1f, sW2tf, sb1, sb2, xs, xd, coef, ms, md);
        int slot_s = atomicAdd(&wsI[CUR_OFF + s], 1);
        float4* m0 = (float4*)(msg + (long long)slot_s * D);
        m0[0] = make_float4(ms[0], ms[1], ms[2], ms[3]);
        m0[1] = make_float4(ms[4], ms[5], ms[6], ms[7]);
        m0[2] = make_float4(ms[8], ms[9], ms[10], ms[11]);
        m0[3] = make_float4(ms[12], ms[13], ms[14], ms[15]);
        int slot_d = atomicAdd(&wsI[CUR_OFF + d], 1);
        float4* m1 = (float4*)(msg + (long long)slot_d * D);
        m1[0] = make_float4(md[0], md[1], md[2], md[3]);
        m1[1] = make_float4(md[4], md[5], md[6], md[7]);
        m1[2] = make_float4(md[8], md[9], md[10], md[11]);
        m1[3] = make_float4(md[12], md[13], md[14], md[15]);
        return;
    }

    // ---------------- bf16 path: 2 lanes per edge ----------------
    int s, d;
    load_edge(ei, e, i64, s, d);
    int a = which ? d : s;                // my message's destination node
    int b = which ? s : d;                // partner node

    // own x row raw (issue early)
    unsigned u[8];
    {
        const uint4* q = (const uint4*)((const ushort_t*)x + (long long)a * D);
        uint4 r0 = q[0], r1 = q[1];
        u[0]=r0.x; u[1]=r0.y; u[2]=r0.z; u[3]=r0.w;
        u[4]=r1.x; u[5]=r1.y; u[6]=r1.z; u[7]=r1.w;
    }

    // early slot claim: latency hides under the MLP math below
    int slot = atomicAdd(&wsI[CUR_OFF + a], 1);

    float dega = (float)wsI[DEG_OFF + a];
    float degb = (float)wsI[DEG_OFF + b];
    // f32 multiply is commutative -> both lanes get the identical coef bits
    float coef = (1.0f / sqrtf(fmaxf(dega, 1e-5f))) * (1.0f / sqrtf(fmaxf(degb, 1e-5f)));

    // partner row via pair shuffle
    unsigned ub[8];
#pragma unroll
    for (int k = 0; k < 8; k++) ub[k] = __shfl_xor(u[k], 1);

    float xa[D], xb[D];
#pragma unroll
    for (int k = 0; k < 8; k++) {
        xa[2 * k]     = lo_bf(u[k]);
        xa[2 * k + 1] = hi_bf(u[k]);
        xb[2 * k]     = lo_bf(ub[k]);
        xb[2 * k + 1] = hi_bf(ub[k]);
    }

    // MLP: h_j = relu(b1[j] + W1[j][0:16].xa + W1[j][16:32].xb); v += W2[:,j] h_j
    // (for which=0 this is exactly the old hs chain; which=1 the hd chain)
    const float* b2f = prep + 64 * 64;
    float va[D];
#pragma unroll
    for (int i = 0; i < D; i++) va[i] = b2f[i];

#pragma unroll 1
    for (int j = 0; j < HID; j++) {
        const float* w = prep + (j << 6);    // uniform -> s_load
        float h0 = w[48], h1 = 0.0f;
#pragma unroll
        for (int k = 0; k < 8; k++) {
            h0 = fmaf(w[k],     xa[k],     h0);
            h1 = fmaf(w[8 + k], xa[8 + k], h1);
        }
#pragma unroll
        for (int k = 0; k < 8; k++) {
            h0 = fmaf(w[16 + k], xb[k],     h0);
            h1 = fmaf(w[24 + k], xb[8 + k], h1);
        }
        float h = fmaxf(h0 + h1, 0.0f);
#pragma unroll
        for (int i = 0; i < D; i++)
            va[i] = fmaf(w[32 + i], h, va[i]);
    }

    // normalize own v
    float nn = 0.0f;
#pragma unroll
    for (int i = 0; i < D; i++) nn = fmaf(va[i], va[i], nn);
    float inv = 1.0f / fmaxf(sqrtf(nn), 1e-12f);
#pragma unroll
    for (int i = 0; i < D; i++) va[i] *= inv;

    // partner's normalized v
    float vo[D];
#pragma unroll
    for (int i = 0; i < D; i++) vo[i] = __shfl_xor(va[i], 1);

    // Householder epilogue (which=0 -> ms chain; which=1 -> md chain; op order
    // identical to the single-lane version)
    float m[D];
    float dotA = 0.0f;
#pragma unroll
    for (int i = 0; i < D; i++) dotA = fmaf(vo[i], xb[i], dotA);
#pragma unroll
    for (int i = 0; i < D; i++) m[i] = fmaf(-2.0f * dotA, vo[i], xb[i]);
    float dotB = 0.0f;
#pragma unroll
    for (int i = 0; i < D; i++) dotB = fmaf(va[i], m[i], dotB);
#pragma unroll
    for (int i = 0; i < D; i++) m[i] = coef * fmaf(-2.0f * dotB, va[i], m[i]);

    float4* m0 = (float4*)(msg + (long long)slot * D);
    m0[0] = make_float4(m[0],  m[1],  m[2],  m[3]);
    m0[1] = make_float4(m[4],  m[5],  m[6],  m[7]);
    m0[2] = make_float4(m[8],  m[9],  m[10], m[11]);
    m0[3] = make_float4(m[12], m[13], m[14], m[15]);
}

// Gather: 4 lanes per node (lane c -> dims 4c..4c+3), unroll-2 accumulation.
__global__ __launch_bounds__(256) void csr_gather_kernel(
    const void* __restrict__ x,
    const void* __restrict__ ei,
    const int* __restrict__ wsI,
    void* __restrict__ out)
{
    __shared__ int sfl[2];
    detect_flags_par(x, ei, sfl);
    __syncthreads();
    int f32 = sfl[0];

    int n = blockIdx.x * 64 + (threadIdx.x >> 2);
    int c = threadIdx.x & 3;
    if (n >= N_NODES) return;

    const int* off = wsI + OFF_OFF;
    const float4* msg4 = (const float4*)(wsI + MSG_OFF_I);

    int beg = off[n], end = off[n + 1];
    float4 a = make_float4(0.0f, 0.0f, 0.0f, 0.0f);
    int it = beg;
    for (; it + 2 <= end; it += 2) {
        float4 u = msg4[(long long)it * 4 + c];
        float4 v = msg4[(long long)(it + 1) * 4 + c];
        a.x += u.x + v.x; a.y += u.y + v.y; a.z += u.z + v.z; a.w += u.w + v.w;
    }
    if (it < end) {
        float4 u = msg4[(long long)it * 4 + c];
        a.x += u.x; a.y += u.y; a.z += u.z; a.w += u.w;
    }

    long long xb = (long long)n * D + 4 * c;
    float4 xv;
    if (f32) {
        xv = *(const float4*)((const float*)x + xb);
    } else {
        uint2 u = *(const uint2*)((const ushort_t*)x + xb);
        xv.x = lo_bf(u.x); xv.y = hi_bf(u.x);
        xv.z = lo_bf(u.y); xv.w = hi_bf(u.y);
    }
    float4 r;
    r.x = fmaxf(xv.x + a.x, 0.0f);
    r.y = fmaxf(xv.y + a.y, 0.0f);
    r.z = fmaxf(xv.z + a.z, 0.0f);
    r.w = fmaxf(xv.w + a.w, 0.0f);
    if (f32) {
        *(float4*)((float*)out + xb) = r;
    } else {
        uint2 o;
        o.x = (unsigned)f2bf(r.x) | ((unsigned)f2bf(r.y) << 16);
        o.y = (unsigned)f2bf(r.z) | ((unsigned)f2bf(r.w) << 16);
        *(uint2*)((ushort_t*)out + xb) = o;
    }
}

// ===========================================================================
// Fallback path (known-good): float atomics into acc
// ===========================================================================
__global__ void fb_init_kernel(float* __restrict__ ws,
                               const void* __restrict__ x,
                               const void* __restrict__ ei) {
    int i = blockIdx.x * blockDim.x + threadIdx.x;
    if (i < FB_FLAGS) ws[i] = 0.0f;
    if (blockIdx.x == 0)
        detect_flags_par(x, ei, (int*)(ws + FB_FLAGS));
}

__global__ void fb_deg_kernel(const void* __restrict__ ei, float* __restrict__ ws) {
    int i64 = ((const int*)(ws + FB_FLAGS))[1];
    int e = blockIdx.x * blockDim.x + threadIdx.x;
    if (e >= N_EDGES) return;
    int s, d;
    load_edge(ei, e, i64, s, d);
    atomicAdd(&ws[s], 1.0f);
    atomicAdd(&ws[d], 1.0f);
}

__global__ __launch_bounds__(256) void fb_edge_kernel(
    const void* __restrict__ x, const void* __restrict__ ei,
    const void* __restrict__ W1, const void* __restrict__ b1,
    const void* __restrict__ W2, const void* __restrict__ b2,
    float* __restrict__ ws)
{
    __shared__ __align__(16) float sW1[HID * 2 * D];
    __shared__ __align__(16) float sW2t[HID * D];
    __shared__ float sb1[HID];
    __shared__ float sb2[D];
    const int* flags = (const int*)(ws + FB_FLAGS);
    int f32 = flags[0], i64 = flags[1];
    stage_weights(W1, b1, W2, b2, f32, sW1, sW2t, sb1, sb2);
    __syncthreads();
    int e = blockIdx.x * blockDim.x + threadIdx.x;
    if (e >= N_EDGES) return;
    int s, d;
    load_edge(ei, e, i64, s, d);
    float xs[D], xd[D];
    load16(x, (long long)s * D, f32, xs);
    load16(x, (long long)d * D, f32, xd);
    float coef = (1.0f / sqrtf(fmaxf(ws[s], 1e-5f))) * (1.0f / sqrtf(fmaxf(ws[d], 1e-5f)));
    float ms[D], md[D];
    edge_math_v4(sW1, sW2t, sb1, sb2, xs, xd, coef, ms, md);
    float* acc = ws + FB_NDEG;
#pragma unroll
    for (int i = 0; i < D; i++) atomicAdd(&acc[(long long)s * D + i], ms[i]);
#pragma unroll
    for (int i = 0; i < D; i++) atomicAdd(&acc[(long long)d * D + i], md[i]);
}

__global__ void fb_finalize_kernel(const void* __restrict__ x,
                                   const float* __restrict__ ws,
                                   void* __restrict__ out)
{
    int f32 = ((const int*)(ws + FB_FLAGS))[0];
    const float* acc = ws + FB_NDEG;
    int i = blockIdx.x * blockDim.x + threadIdx.x;
    if (i >= FB_NACC) return;
    float v = ld_f(x, i, f32) + acc[i];
    v = fmaxf(v, 0.0f);
    if (f32) ((float*)out)[i] = v;
    else     ((__hip_bfloat16*)out)[i] = __float2bfloat16(v);
}

// ===========================================================================
extern "C" void kernel_launch(void* const* d_in, const int* in_sizes, int n_in,
                              void* d_out, int out_size, void* d_ws, size_t ws_size,
                              hipStream_t stream)
{
    const void* x  = d_in[0];
    const void* ei = d_in[1];
    const void* W1 = d_in[2];
    const void* b1 = d_in[3];
    const void* W2 = d_in[4];
    const void* b2 = d_in[5];

    int blk = 256;
    if (ws_size >= CSR_NEEDED_BYTES) {
        int* wsI = (int*)d_ws;
        hipMemsetAsync(d_ws, 0, (size_t)4 * N_NODES * sizeof(int), stream);
        csr_count_kernel<<<(N_EDGES + blk - 1) / blk, blk, 0, stream>>>(ei, x, W1, b1, W2, b2, wsI);
        csr_scan1_kernel<<<SCAN_G, SCAN_B, 0, stream>>>(wsI);
        csr_scan3_kernel<<<SCAN_G, SCAN_B, 0, stream>>>(wsI);
        csr_edge_kernel<<<(2 * N_EDGES + blk - 1) / blk, blk, 0, stream>>>(
            x, ei, W1, b1, W2, b2, (const float*)(wsI + PREP_OFF), wsI);
        csr_gather_kernel<<<(N_NODES + 63) / 64, blk, 0, stream>>>(x, ei, wsI, d_out);
    } else {
        float* ws = (float*)d_ws;
        fb_init_kernel<<<(FB_FLAGS + blk - 1) / blk, blk, 0, stream>>>(ws, x, ei);
        fb_deg_kernel<<<(N_EDGES + blk - 1) / blk, blk, 0, stream>>>(ei, ws);
        fb_edge_kernel<<<(N_EDGES + blk - 1) / blk, blk, 0, stream>>>(x, ei, W1, b1, W2, b2, ws);
        fb_finalize_kernel<<<(FB_NACC + blk - 1) / blk, blk, 0, stream>>>(x, ws, d_out);
    }
}